// Round 1
// baseline (152.827 us; speedup 1.0000x reference)
//
#include <hip/hip_runtime.h>

// Problem: 44 independent tiny MLPs (1 -> 4 -> 8 -> 4 -> 1, relu x3, affine out)
// applied pointwise over B = 400000 samples. Output fp32 (NP,1,B).
//
// Layouts (row-major, from reference):
//   X    : (NP, 1, B)  -> X[l*B + j]
//   lin1 : (NP, 4, 1)  -> lin1[l*4 + i]
//   lin2 : (NP, 8, 4)  -> lin2[l*32 + i*4 + k]
//   lin3 : (NP, 4, 8)  -> lin3[l*32 + i*8 + k]
//   lin4 : (NP, 1, 4)  -> lin4[l*4 + k]
//   b1   : (NP, 4, 1), b2: (NP, 8, 1), b3: (NP, 4, 1), b4: (NP, 1, 1)

#define NP 44
#define BATCH 400000

__device__ __forceinline__ float mlp_one(float x,
                                         const float* __restrict__ w1,
                                         const float* __restrict__ w2,
                                         const float* __restrict__ w3,
                                         const float* __restrict__ w4,
                                         const float* __restrict__ c1,
                                         const float* __restrict__ c2,
                                         const float* __restrict__ c3,
                                         float c4) {
    float h1[4], h2[8], h3[4];
#pragma unroll
    for (int i = 0; i < 4; ++i)
        h1[i] = fmaxf(fmaf(w1[i], x, c1[i]), 0.0f);
#pragma unroll
    for (int i = 0; i < 8; ++i) {
        float a = c2[i];
#pragma unroll
        for (int k = 0; k < 4; ++k)
            a = fmaf(w2[i * 4 + k], h1[k], a);
        h2[i] = fmaxf(a, 0.0f);
    }
#pragma unroll
    for (int i = 0; i < 4; ++i) {
        float a = c3[i];
#pragma unroll
        for (int k = 0; k < 8; ++k)
            a = fmaf(w3[i * 8 + k], h2[k], a);
        h3[i] = fmaxf(a, 0.0f);
    }
    float o = c4;
#pragma unroll
    for (int k = 0; k < 4; ++k)
        o = fmaf(w4[k], h3[k], o);
    return o;
}

__global__ __launch_bounds__(256) void mlp_fwd_kernel(
        const float* __restrict__ X,
        const float* __restrict__ lin1,
        const float* __restrict__ lin2,
        const float* __restrict__ lin3,
        const float* __restrict__ lin4,
        const float* __restrict__ b1,
        const float* __restrict__ b2,
        const float* __restrict__ b3,
        const float* __restrict__ b4,
        float* __restrict__ out) {
    const int l = blockIdx.y;                    // population index (wave-uniform)
    const int j4 = blockIdx.x * blockDim.x + threadIdx.x;  // float4 index in B
    constexpr int B4 = BATCH / 4;                // 100000

    // Per-population parameters: addresses depend only on l (uniform per block)
    // -> compiler emits scalar (s_load) reads into SGPRs.
    float w1[4], w4[4], c1[4], c3[4];
    float w2[32], w3[32];
    float c2[8];
#pragma unroll
    for (int i = 0; i < 4; ++i) {
        w1[i] = lin1[l * 4 + i];
        w4[i] = lin4[l * 4 + i];
        c1[i] = b1[l * 4 + i];
        c3[i] = b3[l * 4 + i];
    }
#pragma unroll
    for (int i = 0; i < 32; ++i) {
        w2[i] = lin2[l * 32 + i];
        w3[i] = lin3[l * 32 + i];
    }
#pragma unroll
    for (int i = 0; i < 8; ++i)
        c2[i] = b2[l * 8 + i];
    const float c4 = b4[l];

    if (j4 >= B4) return;

    const float4* __restrict__ xin = (const float4*)(X + (size_t)l * BATCH);
    float4* __restrict__ po = (float4*)(out + (size_t)l * BATCH);

    float4 x = xin[j4];
    float4 r;
    r.x = mlp_one(x.x, w1, w2, w3, w4, c1, c2, c3, c4);
    r.y = mlp_one(x.y, w1, w2, w3, w4, c1, c2, c3, c4);
    r.z = mlp_one(x.z, w1, w2, w3, w4, c1, c2, c3, c4);
    r.w = mlp_one(x.w, w1, w2, w3, w4, c1, c2, c3, c4);
    po[j4] = r;
}

extern "C" void kernel_launch(void* const* d_in, const int* in_sizes, int n_in,
                              void* d_out, int out_size, void* d_ws, size_t ws_size,
                              hipStream_t stream) {
    const float* X    = (const float*)d_in[0];
    const float* lin1 = (const float*)d_in[1];
    const float* lin2 = (const float*)d_in[2];
    const float* lin3 = (const float*)d_in[3];
    const float* lin4 = (const float*)d_in[4];
    const float* b1   = (const float*)d_in[5];
    const float* b2   = (const float*)d_in[6];
    const float* b3   = (const float*)d_in[7];
    const float* b4   = (const float*)d_in[8];
    float* out = (float*)d_out;

    constexpr int B4 = BATCH / 4;                 // 100000 float4s per population
    dim3 block(256);
    dim3 grid((B4 + 255) / 256, NP);              // (391, 44)
    mlp_fwd_kernel<<<grid, block, 0, stream>>>(X, lin1, lin2, lin3, lin4,
                                               b1, b2, b3, b4, out);
}

// Round 3
// 140.731 us; speedup vs baseline: 1.0860x; 1.0860x over previous
//
#include <hip/hip_runtime.h>

// 44 independent tiny MLPs (1 -> 4 -> 8 -> 4 -> 1, relu x3, affine out),
// pointwise over B = 400000 samples. fp32 in/out.
//
// Round-1 evidence: VALUBusy 72%, HBM 24% -> VALU-issue-bound at ~54 us.
// Round-2/3 change: packed fp32 math (v_pk_fma_f32 / v_pk_max_f32) via clang
// ext_vector_type(2) -> halves VALU issue count. Nontemporal store for the
// write-once output stream (uses clang native vector type; HIP float4 struct
// is rejected by __builtin_nontemporal_store).

#define NP 44
#define BATCH 400000

typedef float v2f __attribute__((ext_vector_type(2)));
typedef float v4f __attribute__((ext_vector_type(4)));

__device__ __forceinline__ v2f splat(float s) { return (v2f){s, s}; }

// One MLP forward over a PAIR of samples (packed fp32).
__device__ __forceinline__ v2f mlp_pair(v2f x,
                                        const float* __restrict__ w1,
                                        const float* __restrict__ w2,
                                        const float* __restrict__ w3,
                                        const float* __restrict__ w4,
                                        const float* __restrict__ c1,
                                        const float* __restrict__ c2,
                                        const float* __restrict__ c3,
                                        float c4) {
    const v2f zero = splat(0.0f);
    v2f h1[4], h2[8], h3[4];
#pragma unroll
    for (int i = 0; i < 4; ++i) {
        v2f a = __builtin_elementwise_fma(splat(w1[i]), x, splat(c1[i]));
        h1[i] = __builtin_elementwise_max(a, zero);         // v_pk_max_f32
    }
#pragma unroll
    for (int i = 0; i < 8; ++i) {
        v2f a = splat(c2[i]);
#pragma unroll
        for (int k = 0; k < 4; ++k)
            a = __builtin_elementwise_fma(splat(w2[i * 4 + k]), h1[k], a);
        h2[i] = __builtin_elementwise_max(a, zero);
    }
#pragma unroll
    for (int i = 0; i < 4; ++i) {
        v2f a = splat(c3[i]);
#pragma unroll
        for (int k = 0; k < 8; ++k)
            a = __builtin_elementwise_fma(splat(w3[i * 8 + k]), h2[k], a);
        h3[i] = __builtin_elementwise_max(a, zero);
    }
    v2f o = splat(c4);
#pragma unroll
    for (int k = 0; k < 4; ++k)
        o = __builtin_elementwise_fma(splat(w4[k]), h3[k], o);
    return o;
}

__global__ __launch_bounds__(256) void mlp_fwd_kernel(
        const float* __restrict__ X,
        const float* __restrict__ lin1,
        const float* __restrict__ lin2,
        const float* __restrict__ lin3,
        const float* __restrict__ lin4,
        const float* __restrict__ b1,
        const float* __restrict__ b2,
        const float* __restrict__ b3,
        const float* __restrict__ b4,
        float* __restrict__ out) {
    const int l = blockIdx.y;                              // population (uniform)
    const int j4 = blockIdx.x * blockDim.x + threadIdx.x;  // float4 index in B
    constexpr int B4 = BATCH / 4;                          // 100000

    // Wave-uniform parameter loads -> SGPRs via s_load.
    float w1[4], w4[4], c1[4], c3[4], w2[32], w3[32], c2[8];
#pragma unroll
    for (int i = 0; i < 4; ++i) {
        w1[i] = lin1[l * 4 + i];
        w4[i] = lin4[l * 4 + i];
        c1[i] = b1[l * 4 + i];
        c3[i] = b3[l * 4 + i];
    }
#pragma unroll
    for (int i = 0; i < 32; ++i) {
        w2[i] = lin2[l * 32 + i];
        w3[i] = lin3[l * 32 + i];
    }
#pragma unroll
    for (int i = 0; i < 8; ++i)
        c2[i] = b2[l * 8 + i];
    const float c4 = b4[l];

    if (j4 >= B4) return;

    const v4f* __restrict__ xin = (const v4f*)(X + (size_t)l * BATCH);
    v4f* po = (v4f*)(out + (size_t)l * BATCH);

    v4f x = xin[j4];
    v2f p0 = mlp_pair((v2f){x.x, x.y}, w1, w2, w3, w4, c1, c2, c3, c4);
    v2f p1 = mlp_pair((v2f){x.z, x.w}, w1, w2, w3, w4, c1, c2, c3, c4);

    v4f r = (v4f){p0.x, p0.y, p1.x, p1.y};
    __builtin_nontemporal_store(r, po + j4);
}

extern "C" void kernel_launch(void* const* d_in, const int* in_sizes, int n_in,
                              void* d_out, int out_size, void* d_ws, size_t ws_size,
                              hipStream_t stream) {
    const float* X    = (const float*)d_in[0];
    const float* lin1 = (const float*)d_in[1];
    const float* lin2 = (const float*)d_in[2];
    const float* lin3 = (const float*)d_in[3];
    const float* lin4 = (const float*)d_in[4];
    const float* b1   = (const float*)d_in[5];
    const float* b2   = (const float*)d_in[6];
    const float* b3   = (const float*)d_in[7];
    const float* b4   = (const float*)d_in[8];
    float* out = (float*)d_out;

    constexpr int B4 = BATCH / 4;                 // 100000 float4s per population
    dim3 block(256);
    dim3 grid((B4 + 255) / 256, NP);              // (391, 44)
    mlp_fwd_kernel<<<grid, block, 0, stream>>>(X, lin1, lin2, lin3, lin4,
                                               b1, b2, b3, b4, out);
}